// Round 1
// 77.776 us; speedup vs baseline: 1.0306x; 1.0306x over previous
//
#include <hip/hip_runtime.h>

#define NQ 11
#define DIM 2048            // 1 << NQ
#define NLAY 6              // 5 variational YZY layers + 1 final
#define NGATES (NLAY * NQ)  // 66 fused 2x2 gates

struct c32 { float re, im; };

// ---------------- GF(2) ring algebra (all compile-time) ----------------
// Ring of CNOTs (q -> q+1 for q=0..9, then 10 -> 0) as a linear map on the
// 11 index bits.  ring_f = the forward permutation (same formula the previous
// kernel used, verified bit-identical to the sequential cascade).
__host__ __device__ constexpr int ring_f(int u) {
    int P = u ^ (u >> 1); P ^= P >> 2; P ^= P >> 4; P ^= P >> 8;
    return (P & 0x3FF) | (((P ^ (u >> 10)) & 1) << 10);
}
// Closed-form inverse: o_i = v_i^v_{i+1} (i=0..8), o9 = v0^v9^v10, o10 = v0^v10.
__host__ __device__ constexpr int ring_inv(int v) {
    int o = 0;
    for (int i = 0; i < 9; i++) o |= (((v >> i) ^ (v >> (i + 1))) & 1) << i;
    o |= (((v >> 0) ^ (v >> 9) ^ (v >> 10)) & 1) << 9;
    o |= (((v >> 0) ^ (v >> 10)) & 1) << 10;
    return o;
}
__host__ __device__ constexpr int ring_pow(int v, int k)     { for (int i = 0; i < k; i++) v = ring_f(v);   return v; }
__host__ __device__ constexpr int ring_inv_pow(int v, int k) { for (int i = 0; i < k; i++) v = ring_inv(v); return v; }
__host__ __device__ constexpr int par11(int x) { x ^= x >> 8; x ^= x >> 4; x ^= x >> 2; x ^= x >> 1; return x & 1; }

// After l rings (data left in place), a gate on logical bit b pairs physical
// positions p ^ MASK, MASK = R^{-l} e_b; the |0>/|1> side of p is
// parity(ROW & p), ROW = row b of R^{l}.
__host__ __device__ constexpr int mask_of(int L, int b) { return ring_inv_pow(1 << b, L); }
__host__ __device__ constexpr int row_of(int L, int b) {
    int m = 0;
    for (int j = 0; j < 11; j++) m |= ((ring_pow(1 << j, L) >> b) & 1) << j;
    return m;
}
// #of cross-wave (LDS-exchange) gates strictly before (L,Q): selects ping/pong.
__host__ __device__ constexpr int cgate_index(int L, int Q) {
    int n = 0;
    for (int l = 0; l <= L; l++)
        for (int q = 0; q < (l < L ? NQ : Q); q++)
            if (mask_of(l, 10 - q) >> 9) n++;
    return n;
}
constexpr bool gf2_checks() {
    for (int u = 0; u < DIM; u++)
        if (ring_inv(ring_f(u)) != u || ring_f(ring_inv(u)) != u) return false;
    for (int l = 0; l < NLAY; l++)
        for (int q = 0; q < NQ; q++) {
            const int b = 10 - q;
            if (mask_of(l, b) == 0) return false;
            if (par11(mask_of(l, b) & row_of(l, b)) != 1) return false;  // partners have opposite sides
        }
    return true;
}
static_assert(gf2_checks(), "GF2 ring algebra broken");

struct RP5T { int v[8]; };
__host__ __device__ constexpr RP5T mkRP5() { RP5T t{}; for (int r = 0; r < 8; r++) t.v[r] = ring_pow(r, 5); return t; }
constexpr RP5T RP5 = mkRP5();

// new = cA*x + cB*y (complex, 2 mul + 6 fma)
__device__ __forceinline__ c32 comb(c32 cA, c32 xx, c32 cB, c32 yy) {
    float re =  cA.re * xx.re;
    re = fmaf(-cA.im, xx.im, re);
    re = fmaf( cB.re, yy.re, re);
    re = fmaf(-cB.im, yy.im, re);
    float im =  cA.re * xx.im;
    im = fmaf( cA.im, xx.re, im);
    im = fmaf( cB.re, yy.im, im);
    im = fmaf( cB.im, yy.re, im);
    return { re, im };
}

// ---------------- one fused 2x2 gate, fully compile-time specialized ----------------
// State: a[r] holds amplitude at physical index p = (tid<<3)|r.
template<int L, int Q>
__device__ __forceinline__ void do_gate(c32 (&a)[8], const c32 (&g)[4],
                                        c32* exA, c32* exB, int tid) {
    constexpr int b     = 10 - Q;
    constexpr int M     = mask_of(L, b);   // physical partner XOR mask
    constexpr int RW    = row_of(L, b);    // side-bit extraction row
    constexpr int mr    = M & 7;           // register part
    constexpr int mt    = M >> 3;          // tid part (6 lane + 2 wave bits)
    constexpr int mlane = mt & 63;
    constexpr int mwav  = mt >> 6;

    const c32 m00 = g[0], m01 = g[1], m10 = g[2], m11 = g[3];
    const int sl = __popc(tid & (RW >> 3)) & 1;          // tid-part of side
    // coefficient sets indexed by cr = parity(RW & r):  total side s = sl ^ cr
    //   s==0: new = m00*own + m01*partner ; s==1: new = m11*own + m10*partner
    const c32 cO0 = sl ? m11 : m00, cP0 = sl ? m10 : m01;   // cr == 0
    const c32 cO1 = sl ? m00 : m11, cP1 = sl ? m01 : m10;   // cr == 1

    if constexpr (mwav != 0) {
        // ---- cross-wave: SoA LDS exchange (ping-pong => single barrier) ----
        c32* buf = (cgate_index(L, Q) & 1) ? exB : exA;
#pragma unroll
        for (int r = 0; r < 8; r++) buf[(r << 8) | tid] = a[r];
        __syncthreads();
#pragma unroll
        for (int r = 0; r < 8; r++) {
            const c32 pv = buf[((r ^ mr) << 8) | (tid ^ mt)];
            const int cr = __popc(r & (RW & 7)) & 1;     // folds to constant
            a[r] = cr ? comb(cO1, a[r], cP1, pv) : comb(cO0, a[r], cP0, pv);
        }
    } else if constexpr (mlane != 0 && mr == 0) {
        // ---- pure lane exchange ----
#pragma unroll
        for (int r = 0; r < 8; r++) {
            const c32 pv { __shfl_xor(a[r].re, mlane, 64), __shfl_xor(a[r].im, mlane, 64) };
            const int cr = __popc(r & (RW & 7)) & 1;
            a[r] = cr ? comb(cO1, a[r], cP1, pv) : comb(cO0, a[r], cP0, pv);
        }
    } else if constexpr (mlane != 0) {
        // ---- lane exchange with register pairing ----
        constexpr int piv = mr & (-mr);
#pragma unroll
        for (int r0 = 0; r0 < 8; r0++) if (!(r0 & piv)) {
            const int r1 = r0 ^ mr;
            const c32 o0 = a[r0], o1 = a[r1];
            const c32 pv0 { __shfl_xor(o1.re, mlane, 64), __shfl_xor(o1.im, mlane, 64) };
            const c32 pv1 { __shfl_xor(o0.re, mlane, 64), __shfl_xor(o0.im, mlane, 64) };
            const int cr0 = __popc(r0 & (RW & 7)) & 1;
            const int cr1 = cr0 ^ (__popc(mr & (RW & 7)) & 1);
            a[r0] = cr0 ? comb(cO1, o0, cP1, pv0) : comb(cO0, o0, cP0, pv0);
            a[r1] = cr1 ? comb(cO1, o1, cP1, pv1) : comb(cO0, o1, cP0, pv1);
        }
    } else {
        // ---- pure in-register pairs (sides provably opposite: RW·M == 1) ----
        constexpr int piv = mr & (-mr);
#pragma unroll
        for (int r0 = 0; r0 < 8; r0++) if (!(r0 & piv)) {
            const int r1 = r0 ^ mr;
            const c32 o0 = a[r0], o1 = a[r1];
            const int cr0 = __popc(r0 & (RW & 7)) & 1;
            a[r0] = cr0 ? comb(cO1, o0, cP1, o1) : comb(cO0, o0, cP0, o1);
            a[r1] = cr0 ? comb(cO0, o1, cP0, o0) : comb(cO1, o1, cP1, o0);
        }
    }
}

template<int L, int Q>
__device__ __forceinline__ void run_gates(c32 (&a)[8], const c32 (*gates)[4],
                                          c32* exA, c32* exB, int tid) {
    do_gate<L, Q>(a, gates[L * NQ + Q], exA, exB, tid);
    if constexpr (Q < NQ - 1)       run_gates<L, Q + 1>(a, gates, exA, exB, tid);
    else if constexpr (L < NLAY - 1) run_gates<L + 1, 0>(a, gates, exA, exB, tid);
}

__global__ __launch_bounds__(256) void qsim_kernel(
    const float* __restrict__ x,   // [B,1,NQ] f32
    const float* __restrict__ w,   // [198] f32
    float* __restrict__ out)       // f32: [B,32,32] REAL block, then IMAG block
{
    __shared__ c32 exA[DIM];
    __shared__ c32 exB[DIM];
    __shared__ c32 gates[NGATES][4];

    const int b = blockIdx.x;
    const int tid = threadIdx.x;

    // ---- fused YZY matrices (embedding folded into layer 0) ----
    if (tid < NGATES) {
        const int l = tid / NQ, q = tid % NQ;
        const float* p = &w[l * 3 * NQ + q * 3];
        float c0, s0, cz, sz, c2, s2;
        sincosf(0.5f * p[0], &s0, &c0);
        sincosf(0.5f * p[1], &sz, &cz);
        sincosf(0.5f * p[2], &s2, &c2);
        c32 A00 = {  cz * c0, -sz * c0 };
        c32 A01 = { -cz * s0,  sz * s0 };
        c32 A10 = {  cz * s0,  sz * s0 };
        c32 A11 = {  cz * c0,  sz * c0 };
        c32 M00 = { c2 * A00.re - s2 * A10.re, c2 * A00.im - s2 * A10.im };
        c32 M01 = { c2 * A01.re - s2 * A11.re, c2 * A01.im - s2 * A11.im };
        c32 M10 = { s2 * A00.re + c2 * A10.re, s2 * A00.im + c2 * A10.im };
        c32 M11 = { s2 * A01.re + c2 * A11.re, s2 * A01.im + c2 * A11.im };
        if (l == 0) {
            float ce, se;
            sincosf(0.5f * x[b * NQ + q], &se, &ce);
            c32 N00 = { M00.re * ce + M01.re * se, M00.im * ce + M01.im * se };
            c32 N01 = { M01.re * ce - M00.re * se, M01.im * ce - M00.im * se };
            c32 N10 = { M10.re * ce + M11.re * se, M10.im * ce + M11.im * se };
            c32 N11 = { M11.re * ce - M10.re * se, M11.im * ce - M10.im * se };
            M00 = N00; M01 = N01; M10 = N10; M11 = N11;
        }
        gates[tid][0] = M00; gates[tid][1] = M01;
        gates[tid][2] = M10; gates[tid][3] = M11;
    }

    // ---- |0...0>, 8 amplitudes per lane in registers ----
    c32 a[8];
#pragma unroll
    for (int r = 0; r < 8; r++) a[r] = { 0.f, 0.f };
    if (tid == 0) a[0].re = 1.f;
    __syncthreads();

    // ---- full circuit: 66 gates, CNOT rings folded into index masks ----
    run_gates<0, 0>(a, gates, exA, exB, tid);

    // ---- unscramble the 5 accumulated rings: logical = R^5 * physical ----
    __syncthreads();
    int T = tid << 3;
#pragma unroll
    for (int k = 0; k < 5; k++) T = ring_f(T);
#pragma unroll
    for (int r = 0; r < 8; r++) exA[T ^ RP5.v[r]] = a[r];
    __syncthreads();

    // ---- partial trace keeping the LAST 5 qubits (low bits) ----
    // rho[b][j][k] = sum_{i<64} psi[i*32+j] * conj(psi[i*32+k]); 2x2 block/thread
    const int j0 = (tid >> 4) << 1, k0 = (tid & 15) << 1;
    float r00re = 0.f, r00im = 0.f, r01re = 0.f, r01im = 0.f;
    float r10re = 0.f, r10im = 0.f, r11re = 0.f, r11im = 0.f;
#pragma unroll 8
    for (int i = 0; i < 64; i++) {
        const c32 A0 = exA[i * 32 + j0], A1 = exA[i * 32 + j0 + 1];
        const c32 B0 = exA[i * 32 + k0], B1 = exA[i * 32 + k0 + 1];
        r00re = fmaf(A0.re, B0.re, fmaf( A0.im, B0.im, r00re));
        r00im = fmaf(A0.im, B0.re, fmaf(-A0.re, B0.im, r00im));
        r01re = fmaf(A0.re, B1.re, fmaf( A0.im, B1.im, r01re));
        r01im = fmaf(A0.im, B1.re, fmaf(-A0.re, B1.im, r01im));
        r10re = fmaf(A1.re, B0.re, fmaf( A1.im, B0.im, r10re));
        r10im = fmaf(A1.im, B0.re, fmaf(-A1.re, B0.im, r10im));
        r11re = fmaf(A1.re, B1.re, fmaf( A1.im, B1.im, r11re));
        r11im = fmaf(A1.im, B1.re, fmaf(-A1.re, B1.im, r11im));
    }
    // PLANAR f32 layout: real block [0,16384), imag block [16384,32768).
    float* o = out + b * 1024;
    o[ j0      * 32 + k0    ] = r00re;
    o[ j0      * 32 + k0 + 1] = r01re;
    o[(j0 + 1) * 32 + k0    ] = r10re;
    o[(j0 + 1) * 32 + k0 + 1] = r11re;
    o += 16384;
    o[ j0      * 32 + k0    ] = r00im;
    o[ j0      * 32 + k0 + 1] = r01im;
    o[(j0 + 1) * 32 + k0    ] = r10im;
    o[(j0 + 1) * 32 + k0 + 1] = r11im;
}

extern "C" void kernel_launch(void* const* d_in, const int* in_sizes, int n_in,
                              void* d_out, int out_size, void* d_ws, size_t ws_size,
                              hipStream_t stream) {
    const float* x = (const float*)d_in[0];   // [B,1,NQ] f32
    const float* w = (const float*)d_in[1];   // [198] f32
    float* out = (float*)d_out;
    qsim_kernel<<<16, 256, 0, stream>>>(x, w, out);
}

// Round 2
// 73.403 us; speedup vs baseline: 1.0920x; 1.0596x over previous
//
#include <hip/hip_runtime.h>

#define NQ 11
#define DIM 2048            // 1 << NQ
#define NLAY 6              // 5 variational YZY layers + 1 final
#define NGATES (NLAY * NQ)  // 66 fused 2x2 gates

struct c32 { float re, im; };

// ---------------- GF(2) ring algebra (all compile-time) ----------------
__host__ __device__ constexpr int ring_f(int u) {
    int P = u ^ (u >> 1); P ^= P >> 2; P ^= P >> 4; P ^= P >> 8;
    return (P & 0x3FF) | (((P ^ (u >> 10)) & 1) << 10);
}
__host__ __device__ constexpr int ring_inv(int v) {
    int o = 0;
    for (int i = 0; i < 9; i++) o |= (((v >> i) ^ (v >> (i + 1))) & 1) << i;
    o |= (((v >> 0) ^ (v >> 9) ^ (v >> 10)) & 1) << 9;
    o |= (((v >> 0) ^ (v >> 10)) & 1) << 10;
    return o;
}
__host__ __device__ constexpr int ring_pow(int v, int k)     { for (int i = 0; i < k; i++) v = ring_f(v);   return v; }
__host__ __device__ constexpr int ring_inv_pow(int v, int k) { for (int i = 0; i < k; i++) v = ring_inv(v); return v; }
__host__ __device__ constexpr int par11(int x) { x ^= x >> 8; x ^= x >> 4; x ^= x >> 2; x ^= x >> 1; return x & 1; }

// After l rings (data left in place), a gate on logical bit b pairs physical
// positions p ^ MASK, MASK = R^{-l} e_b; side(p) = parity(ROW & p), ROW = row b of R^l.
__host__ __device__ constexpr int mask_of(int L, int b) { return ring_inv_pow(1 << b, L); }
__host__ __device__ constexpr int row_of(int L, int b) {
    int m = 0;
    for (int j = 0; j < 11; j++) m |= ((ring_pow(1 << j, L) >> b) & 1) << j;
    return m;
}
constexpr bool gf2_checks() {
    for (int u = 0; u < DIM; u++)
        if (ring_inv(ring_f(u)) != u || ring_f(ring_inv(u)) != u) return false;
    for (int l = 0; l < NLAY; l++)
        for (int q = 0; q < NQ; q++) {
            const int b = 10 - q;
            if (mask_of(l, b) == 0) return false;
            if (par11(mask_of(l, b) & row_of(l, b)) != 1) return false;
        }
    return true;
}
static_assert(gf2_checks(), "GF2 ring algebra broken");

// ---------------- 11x11 GF(2) matrices (columns as 11-bit ints) ----------------
struct M11 { int col[11]; };

__host__ __device__ constexpr int mapv(const M11& A, int x) {
    int y = 0;
    for (int i = 0; i < 11; ++i) if ((x >> i) & 1) y ^= A.col[i];
    return y;
}
__host__ __device__ constexpr M11 inv11(const M11& A) {
    unsigned rowa[11] = {};
    for (int r = 0; r < 11; ++r) {
        unsigned v = 0;
        for (int c = 0; c < 11; ++c) v |= ((unsigned)(A.col[c] >> r) & 1u) << c;
        rowa[r] = v | (1u << (11 + r));
    }
    for (int c = 0; c < 11; ++c) {
        int piv = -1;
        for (int r = c; r < 11; ++r) if ((rowa[r] >> c) & 1u) { piv = r; break; }
        if (piv < 0) continue;                       // singular -> caught by check
        unsigned tmp = rowa[c]; rowa[c] = rowa[piv]; rowa[piv] = tmp;
        for (int r = 0; r < 11; ++r)
            if (r != c && ((rowa[r] >> c) & 1u)) rowa[r] ^= rowa[c];
    }
    M11 R{};
    for (int c = 0; c < 11; ++c) {
        int v = 0;
        for (int r = 0; r < 11; ++r) v |= (int)((rowa[r] >> (11 + c)) & 1u) << r;
        R.col[c] = v;
    }
    return R;
}
// t-index (11 bits, t = (tid<<3)|r) -> SoA LDS slot (r<<8)|tid.  Linear bijection.
__host__ __device__ constexpr int rotv(int t) { return ((t & 7) << 8) | (t >> 3); }

// ---------------- the layout plan (greedy segmentation + per-segment phi) ------
struct Plan {
    int kind[NGATES];       // 0 = wave-local gate, 1 = LDS-exchange cut
    int tmask[NGATES];      // wave-local: pairing mask over t
    int trow[NGATES];       // side row over t (new layout for cuts)
    int gcol[NGATES][11];   // cut: columns of slot-map matrix (t_new -> old SoA slot)
    int dslot[NGATES];      // cut: partner slot xor
    int cidx[NGATES];       // cut ordinal (ping-pong buffer select)
    int ucol[11];           // final unscramble: logical = U(t)
    int ncuts;
    int ok;
};

__host__ __device__ constexpr int topbit11(int x) { int b = -1; for (int i = 0; i < 11; ++i) if ((x >> i) & 1) b = i; return b; }

__host__ __device__ constexpr int reduce_ech(int r, const int* ech, int ne) {
    bool ch = true;
    while (ch && r) {
        ch = false;
        for (int i = 0; i < ne; ++i) {
            const int tb = topbit11(ech[i]);
            if (tb >= 0 && ((r >> tb) & 1)) { r ^= ech[i]; ch = true; }
        }
    }
    return r;
}

__host__ __device__ constexpr Plan mkplan() {
    Plan P{};
    P.ok = 1;
    constexpr int MAXSEG = 16;
    M11 C[MAXSEG] = {};
    int nb[MAXSEG] = {};
    int lastseg = 0;
    // ---- pass 1: greedy segmentation; cut when span rank would exceed 9 ----
    {
        int ech[11] = {}; int ne = 0; int seg = 0;
        for (int g = 0; g < NGATES; ++g) {
            const int m = mask_of(g / 11, 10 - g % 11);
            const int r = reduce_ech(m, ech, ne);
            if (r != 0 && ne == 9) {
                P.kind[g] = 1; P.cidx[g] = P.ncuts++;
                seg++; ne = 0;
                if (seg >= MAXSEG) { P.ok = 0; return P; }
            } else {
                P.kind[g] = 0;
                if (r != 0) { ech[ne++] = r; C[seg].col[nb[seg]++] = m; }
            }
        }
        lastseg = seg;
        // complete each segment's columns to an invertible matrix with unit vectors
        for (int s = 0; s <= seg; ++s) {
            for (int j = 0; j < 11 && nb[s] < 11; ++j) {
                int e2[11] = {}; int n2 = 0;
                for (int i = 0; i < nb[s]; ++i) {
                    const int rr = reduce_ech(C[s].col[i], e2, n2);
                    if (rr) e2[n2++] = rr;
                }
                if (reduce_ech(1 << j, e2, n2) != 0) C[s].col[nb[s]++] = 1 << j;
            }
            if (nb[s] != 11) P.ok = 0;
        }
    }
    // ---- pass 2: per-gate constants ----
    {
        M11 IC[MAXSEG] = {};
        for (int s = 0; s <= lastseg; ++s) {
            IC[s] = inv11(C[s]);
            for (int i = 0; i < 11; ++i)
                if (mapv(IC[s], C[s].col[i]) != (1 << i)) P.ok = 0;
        }
        int cur = 0;
        for (int g = 0; g < NGATES; ++g) {
            const int L = g / 11, b = 10 - g % 11;
            const int m = mask_of(L, b), rw = row_of(L, b);
            if (P.kind[g] == 0) {
                const int tm = mapv(IC[cur], m);
                P.tmask[g] = tm;
                int tr = 0;
                for (int i = 0; i < 11; ++i) tr |= par11(rw & C[cur].col[i]) << i;
                P.trow[g] = tr;
                if ((tm >> 9) != 0 || tm == 0) P.ok = 0;  // must be wave-local
                if (par11(tr & tm) != 1) P.ok = 0;        // partners on opposite sides
            } else {
                const int so = cur, sn = cur + 1;
                for (int i = 0; i < 11; ++i)
                    P.gcol[g][i] = rotv(mapv(IC[so], C[sn].col[i]));
                P.dslot[g] = rotv(mapv(IC[so], m));
                int tr = 0;
                for (int i = 0; i < 11; ++i) tr |= par11(rw & C[sn].col[i]) << i;
                P.trow[g] = tr;
                cur = sn;
            }
        }
        if (cur != lastseg) P.ok = 0;
        for (int i = 0; i < 11; ++i) P.ucol[i] = ring_pow(C[cur].col[i], 5);
    }
    return P;
}

constexpr Plan PL = mkplan();
static_assert(PL.ok == 1, "layout plan construction failed");
static_assert(PL.ncuts == 6, "expected exactly 6 LDS exchanges");

// new = cA*x + cB*y (complex, 2 mul + 6 fma)
__device__ __forceinline__ c32 comb(c32 cA, c32 xx, c32 cB, c32 yy) {
    float re =  cA.re * xx.re;
    re = fmaf(-cA.im, xx.im, re);
    re = fmaf( cB.re, yy.re, re);
    re = fmaf(-cB.im, yy.im, re);
    float im =  cA.re * xx.im;
    im = fmaf( cA.im, xx.re, im);
    im = fmaf( cB.re, yy.im, im);
    im = fmaf( cB.im, yy.re, im);
    return { re, im };
}

// ---------------- wave-local gate (register pair or lane shuffle) --------------
template<int g>
__device__ __forceinline__ void seg_gate(c32 (&a)[8], const c32 (&gm)[4], int tid) {
    constexpr int TMv = PL.tmask[g];
    constexpr int TRv = PL.trow[g];
    constexpr int mr = TMv & 7;
    constexpr int mlane = (TMv >> 3) & 63;
    static_assert((TMv >> 9) == 0 && TMv != 0, "seg gate must be wave-local");

    const c32 m00 = gm[0], m01 = gm[1], m10 = gm[2], m11 = gm[3];
    const int sl = __popc(tid & (TRv >> 3)) & 1;
    const c32 cO0 = sl ? m11 : m00, cP0 = sl ? m10 : m01;   // side-parity 0 (within regs)
    const c32 cO1 = sl ? m00 : m11, cP1 = sl ? m01 : m10;   // side-parity 1

    if constexpr (mlane != 0 && mr == 0) {
#pragma unroll
        for (int r = 0; r < 8; ++r) {
            const c32 pv { __shfl_xor(a[r].re, mlane, 64), __shfl_xor(a[r].im, mlane, 64) };
            const int cr = __popc(r & (TRv & 7)) & 1;
            a[r] = cr ? comb(cO1, a[r], cP1, pv) : comb(cO0, a[r], cP0, pv);
        }
    } else if constexpr (mlane != 0) {
        constexpr int piv = mr & (-mr);
#pragma unroll
        for (int r0 = 0; r0 < 8; ++r0) if (!(r0 & piv)) {
            const int r1 = r0 ^ mr;
            const c32 o0 = a[r0], o1 = a[r1];
            const c32 pv0 { __shfl_xor(o1.re, mlane, 64), __shfl_xor(o1.im, mlane, 64) };
            const c32 pv1 { __shfl_xor(o0.re, mlane, 64), __shfl_xor(o0.im, mlane, 64) };
            const int cr0 = __popc(r0 & (TRv & 7)) & 1;
            const int cr1 = cr0 ^ (__popc(mr & (TRv & 7)) & 1);
            a[r0] = cr0 ? comb(cO1, o0, cP1, pv0) : comb(cO0, o0, cP0, pv0);
            a[r1] = cr1 ? comb(cO1, o1, cP1, pv1) : comb(cO0, o1, cP0, pv1);
        }
    } else {
        constexpr int piv = mr & (-mr);
#pragma unroll
        for (int r0 = 0; r0 < 8; ++r0) if (!(r0 & piv)) {
            const int r1 = r0 ^ mr;
            const c32 o0 = a[r0], o1 = a[r1];
            const int cr0 = __popc(r0 & (TRv & 7)) & 1;
            a[r0] = cr0 ? comb(cO1, o0, cP1, o1) : comb(cO0, o0, cP0, o1);
            a[r1] = cr0 ? comb(cO0, o1, cP0, o0) : comb(cO1, o1, cP1, o0);
        }
    }
}

// ---------------- LDS-exchange gate + layout transition (one barrier) ----------
template<int g>
__device__ __forceinline__ void cut_gate(c32 (&a)[8], const c32 (&gm)[4],
                                         c32* exA, c32* exB, int tid) {
    constexpr int TRv = PL.trow[g];
    constexpr int DS  = PL.dslot[g];
    constexpr int CI  = PL.cidx[g];
    constexpr int G0 = PL.gcol[g][0], G1 = PL.gcol[g][1], G2 = PL.gcol[g][2];
    constexpr int G3 = PL.gcol[g][3], G4 = PL.gcol[g][4], G5 = PL.gcol[g][5];
    constexpr int G6 = PL.gcol[g][6], G7 = PL.gcol[g][7], G8 = PL.gcol[g][8];
    constexpr int G9 = PL.gcol[g][9], G10 = PL.gcol[g][10];

    c32* buf = (CI & 1) ? exB : exA;
#pragma unroll
    for (int r = 0; r < 8; ++r) buf[(r << 8) | tid] = a[r];   // SoA: conflict-free
    __syncthreads();

    int base = 0;                               // old SoA slot of phys(C_new(tid<<3))
    base ^= (-((tid >> 0) & 1)) & G3;
    base ^= (-((tid >> 1) & 1)) & G4;
    base ^= (-((tid >> 2) & 1)) & G5;
    base ^= (-((tid >> 3) & 1)) & G6;
    base ^= (-((tid >> 4) & 1)) & G7;
    base ^= (-((tid >> 5) & 1)) & G8;
    base ^= (-((tid >> 6) & 1)) & G9;
    base ^= (-((tid >> 7) & 1)) & G10;

    const c32 m00 = gm[0], m01 = gm[1], m10 = gm[2], m11 = gm[3];
    const int sl = __popc(tid & (TRv >> 3)) & 1;
    const c32 cO0 = sl ? m11 : m00, cP0 = sl ? m10 : m01;
    const c32 cO1 = sl ? m00 : m11, cP1 = sl ? m01 : m10;
#pragma unroll
    for (int r = 0; r < 8; ++r) {
        const int so = base ^ (((r & 1) ? G0 : 0) ^ ((r & 2) ? G1 : 0) ^ ((r & 4) ? G2 : 0));
        const c32 own = buf[so];
        const c32 par = buf[so ^ DS];
        const int cr = __popc(r & (TRv & 7)) & 1;
        a[r] = cr ? comb(cO1, own, cP1, par) : comb(cO0, own, cP0, par);
    }
}

template<int g>
__device__ __forceinline__ void run_all(c32 (&a)[8], const c32 (*gates)[4],
                                        c32* exA, c32* exB, int tid) {
    if constexpr (PL.kind[g] == 1) cut_gate<g>(a, gates[g], exA, exB, tid);
    else                           seg_gate<g>(a, gates[g], tid);
    if constexpr (g + 1 < NGATES) run_all<g + 1>(a, gates, exA, exB, tid);
}

__global__ __launch_bounds__(256) void qsim_kernel(
    const float* __restrict__ x,   // [B,1,NQ] f32
    const float* __restrict__ w,   // [198] f32
    float* __restrict__ out)       // f32: [B,32,32] REAL block, then IMAG block
{
    __shared__ c32 exA[DIM];
    __shared__ c32 exB[DIM];
    __shared__ c32 gates[NGATES][4];

    const int b = blockIdx.x;
    const int tid = threadIdx.x;

    // ---- fused YZY matrices (embedding folded into layer 0) ----
    if (tid < NGATES) {
        const int l = tid / NQ, q = tid % NQ;
        const float* p = &w[l * 3 * NQ + q * 3];
        float c0, s0, cz, sz, c2, s2;
        sincosf(0.5f * p[0], &s0, &c0);
        sincosf(0.5f * p[1], &sz, &cz);
        sincosf(0.5f * p[2], &s2, &c2);
        c32 A00 = {  cz * c0, -sz * c0 };
        c32 A01 = { -cz * s0,  sz * s0 };
        c32 A10 = {  cz * s0,  sz * s0 };
        c32 A11 = {  cz * c0,  sz * c0 };
        c32 M00 = { c2 * A00.re - s2 * A10.re, c2 * A00.im - s2 * A10.im };
        c32 M01 = { c2 * A01.re - s2 * A11.re, c2 * A01.im - s2 * A11.im };
        c32 M10 = { s2 * A00.re + c2 * A10.re, s2 * A00.im + c2 * A10.im };
        c32 M11 = { s2 * A01.re + c2 * A11.re, s2 * A01.im + c2 * A11.im };
        if (l == 0) {
            float ce, se;
            sincosf(0.5f * x[b * NQ + q], &se, &ce);
            c32 N00 = { M00.re * ce + M01.re * se, M00.im * ce + M01.im * se };
            c32 N01 = { M01.re * ce - M00.re * se, M01.im * ce - M00.im * se };
            c32 N10 = { M10.re * ce + M11.re * se, M10.im * ce + M11.im * se };
            c32 N11 = { M11.re * ce - M10.re * se, M11.im * ce - M10.im * se };
            M00 = N00; M01 = N01; M10 = N10; M11 = N11;
        }
        gates[tid][0] = M00; gates[tid][1] = M01;
        gates[tid][2] = M10; gates[tid][3] = M11;
    }

    // ---- |0...0>, 8 amplitudes per lane in registers (phys 0 -> t 0 always) ----
    c32 a[8];
#pragma unroll
    for (int r = 0; r < 8; ++r) a[r] = { 0.f, 0.f };
    if (tid == 0) a[0].re = 1.f;
    __syncthreads();

    // ---- full circuit: 21 register gates + 39 single-bit shuffles + 6 LDS cuts ----
    run_all<0>(a, gates, exA, exB, tid);

    // ---- unscramble to logical order: logical = R^5(C_last(t)) ----
    constexpr int U0 = PL.ucol[0], U1 = PL.ucol[1], U2 = PL.ucol[2];
    constexpr int U3 = PL.ucol[3], U4 = PL.ucol[4], U5 = PL.ucol[5];
    constexpr int U6 = PL.ucol[6], U7 = PL.ucol[7], U8 = PL.ucol[8];
    constexpr int U9 = PL.ucol[9], U10 = PL.ucol[10];
    c32* fb = (PL.ncuts & 1) ? exB : exA;     // the buffer NOT used by the last cut
    int T = 0;
    T ^= (-((tid >> 0) & 1)) & U3;
    T ^= (-((tid >> 1) & 1)) & U4;
    T ^= (-((tid >> 2) & 1)) & U5;
    T ^= (-((tid >> 3) & 1)) & U6;
    T ^= (-((tid >> 4) & 1)) & U7;
    T ^= (-((tid >> 5) & 1)) & U8;
    T ^= (-((tid >> 6) & 1)) & U9;
    T ^= (-((tid >> 7) & 1)) & U10;
#pragma unroll
    for (int r = 0; r < 8; ++r) {
        const int off = ((r & 1) ? U0 : 0) ^ ((r & 2) ? U1 : 0) ^ ((r & 4) ? U2 : 0);
        fb[T ^ off] = a[r];
    }
    __syncthreads();

    // ---- partial trace keeping the LAST 5 qubits (low bits) ----
    // rho[b][j][k] = sum_{i<64} psi[i*32+j] * conj(psi[i*32+k]); 2x2 block/thread
    const int j0 = (tid >> 4) << 1, k0 = (tid & 15) << 1;
    float r00re = 0.f, r00im = 0.f, r01re = 0.f, r01im = 0.f;
    float r10re = 0.f, r10im = 0.f, r11re = 0.f, r11im = 0.f;
#pragma unroll 8
    for (int i = 0; i < 64; i++) {
        const c32 A0 = fb[i * 32 + j0], A1 = fb[i * 32 + j0 + 1];
        const c32 B0 = fb[i * 32 + k0], B1 = fb[i * 32 + k0 + 1];
        r00re = fmaf(A0.re, B0.re, fmaf( A0.im, B0.im, r00re));
        r00im = fmaf(A0.im, B0.re, fmaf(-A0.re, B0.im, r00im));
        r01re = fmaf(A0.re, B1.re, fmaf( A0.im, B1.im, r01re));
        r01im = fmaf(A0.im, B1.re, fmaf(-A0.re, B1.im, r01im));
        r10re = fmaf(A1.re, B0.re, fmaf( A1.im, B0.im, r10re));
        r10im = fmaf(A1.im, B0.re, fmaf(-A1.re, B0.im, r10im));
        r11re = fmaf(A1.re, B1.re, fmaf( A1.im, B1.im, r11re));
        r11im = fmaf(A1.im, B1.re, fmaf(-A1.re, B1.im, r11im));
    }
    // PLANAR f32 layout: real block [0,16384), imag block [16384,32768).
    float* o = out + b * 1024;
    o[ j0      * 32 + k0    ] = r00re;
    o[ j0      * 32 + k0 + 1] = r01re;
    o[(j0 + 1) * 32 + k0    ] = r10re;
    o[(j0 + 1) * 32 + k0 + 1] = r11re;
    o += 16384;
    o[ j0      * 32 + k0    ] = r00im;
    o[ j0      * 32 + k0 + 1] = r01im;
    o[(j0 + 1) * 32 + k0    ] = r10im;
    o[(j0 + 1) * 32 + k0 + 1] = r11im;
}

extern "C" void kernel_launch(void* const* d_in, const int* in_sizes, int n_in,
                              void* d_out, int out_size, void* d_ws, size_t ws_size,
                              hipStream_t stream) {
    const float* x = (const float*)d_in[0];   // [B,1,NQ] f32
    const float* w = (const float*)d_in[1];   // [198] f32
    float* out = (float*)d_out;
    qsim_kernel<<<16, 256, 0, stream>>>(x, w, out);
}

// Round 3
// 71.938 us; speedup vs baseline: 1.1143x; 1.0204x over previous
//
#include <hip/hip_runtime.h>

#define NQ 11
#define DIM 2048            // 1 << NQ
#define NLAY 6              // 5 variational YZY layers + 1 final
#define NGATES (NLAY * NQ)  // 66 fused 2x2 gates

struct c32 { float re, im; };
struct __align__(16) c32x2 { c32 a, b; };   // {own-coef, partner-coef}, one b128

// ---------------- GF(2) ring algebra (all compile-time) ----------------
__host__ __device__ constexpr int ring_f(int u) {
    int P = u ^ (u >> 1); P ^= P >> 2; P ^= P >> 4; P ^= P >> 8;
    return (P & 0x3FF) | (((P ^ (u >> 10)) & 1) << 10);
}
__host__ __device__ constexpr int ring_inv(int v) {
    int o = 0;
    for (int i = 0; i < 9; i++) o |= (((v >> i) ^ (v >> (i + 1))) & 1) << i;
    o |= (((v >> 0) ^ (v >> 9) ^ (v >> 10)) & 1) << 9;
    o |= (((v >> 0) ^ (v >> 10)) & 1) << 10;
    return o;
}
__host__ __device__ constexpr int ring_pow(int v, int k)     { for (int i = 0; i < k; i++) v = ring_f(v);   return v; }
__host__ __device__ constexpr int ring_inv_pow(int v, int k) { for (int i = 0; i < k; i++) v = ring_inv(v); return v; }
__host__ __device__ constexpr int par11(int x) { x ^= x >> 8; x ^= x >> 4; x ^= x >> 2; x ^= x >> 1; return x & 1; }

__host__ __device__ constexpr int mask_of(int L, int b) { return ring_inv_pow(1 << b, L); }
__host__ __device__ constexpr int row_of(int L, int b) {
    int m = 0;
    for (int j = 0; j < 11; j++) m |= ((ring_pow(1 << j, L) >> b) & 1) << j;
    return m;
}
constexpr bool gf2_checks() {
    for (int u = 0; u < DIM; u++)
        if (ring_inv(ring_f(u)) != u || ring_f(ring_inv(u)) != u) return false;
    for (int l = 0; l < NLAY; l++)
        for (int q = 0; q < NQ; q++) {
            const int b = 10 - q;
            if (mask_of(l, b) == 0) return false;
            if (par11(mask_of(l, b) & row_of(l, b)) != 1) return false;
        }
    return true;
}
static_assert(gf2_checks(), "GF2 ring algebra broken");

// ---------------- 11x11 GF(2) matrices (columns as 11-bit ints) ----------------
struct M11 { int col[11]; };

__host__ __device__ constexpr int mapv(const M11& A, int x) {
    int y = 0;
    for (int i = 0; i < 11; ++i) if ((x >> i) & 1) y ^= A.col[i];
    return y;
}
__host__ __device__ constexpr M11 inv11(const M11& A) {
    unsigned rowa[11] = {};
    for (int r = 0; r < 11; ++r) {
        unsigned v = 0;
        for (int c = 0; c < 11; ++c) v |= ((unsigned)(A.col[c] >> r) & 1u) << c;
        rowa[r] = v | (1u << (11 + r));
    }
    for (int c = 0; c < 11; ++c) {
        int piv = -1;
        for (int r = c; r < 11; ++r) if ((rowa[r] >> c) & 1u) { piv = r; break; }
        if (piv < 0) continue;
        unsigned tmp = rowa[c]; rowa[c] = rowa[piv]; rowa[piv] = tmp;
        for (int r = 0; r < 11; ++r)
            if (r != c && ((rowa[r] >> c) & 1u)) rowa[r] ^= rowa[c];
    }
    M11 R{};
    for (int c = 0; c < 11; ++c) {
        int v = 0;
        for (int r = 0; r < 11; ++r) v |= (int)((rowa[r] >> (11 + c)) & 1u) << r;
        R.col[c] = v;
    }
    return R;
}
// t-index (11 bits, t = (tid<<3)|r) -> SoA LDS slot (r<<8)|tid.  Linear bijection.
__host__ __device__ constexpr int rotv(int t) { return ((t & 7) << 8) | (t >> 3); }

// ---------------- the layout plan (greedy segmentation + per-segment phi) ------
struct Plan {
    int kind[NGATES];       // 0 = wave-local gate, 1 = LDS-exchange cut
    int tmask[NGATES];      // wave-local: pairing mask over t
    int trow[NGATES];       // side row over t (new layout for cuts)
    int gcol[NGATES][11];   // cut: columns of slot-map matrix (t_new -> old SoA slot)
    int dslot[NGATES];      // cut: partner slot xor
    int cidx[NGATES];       // cut ordinal (ping-pong buffer select)
    int ucol[11];           // final unscramble: logical = U(t)
    int ncuts;
    int ok;
};

__host__ __device__ constexpr int topbit11(int x) { int b = -1; for (int i = 0; i < 11; ++i) if ((x >> i) & 1) b = i; return b; }

__host__ __device__ constexpr int reduce_ech(int r, const int* ech, int ne) {
    bool ch = true;
    while (ch && r) {
        ch = false;
        for (int i = 0; i < ne; ++i) {
            const int tb = topbit11(ech[i]);
            if (tb >= 0 && ((r >> tb) & 1)) { r ^= ech[i]; ch = true; }
        }
    }
    return r;
}

__host__ __device__ constexpr Plan mkplan() {
    Plan P{};
    P.ok = 1;
    constexpr int MAXSEG = 16;
    M11 C[MAXSEG] = {};
    int nb[MAXSEG] = {};
    int lastseg = 0;
    // ---- pass 1: greedy segmentation; cut when span rank would exceed 9 ----
    {
        int ech[11] = {}; int ne = 0; int seg = 0;
        for (int g = 0; g < NGATES; ++g) {
            const int m = mask_of(g / 11, 10 - g % 11);
            const int r = reduce_ech(m, ech, ne);
            if (r != 0 && ne == 9) {
                P.kind[g] = 1; P.cidx[g] = P.ncuts++;
                seg++; ne = 0;
                if (seg >= MAXSEG) { P.ok = 0; return P; }
            } else {
                P.kind[g] = 0;
                if (r != 0) { ech[ne++] = r; C[seg].col[nb[seg]++] = m; }
            }
        }
        lastseg = seg;
        for (int s = 0; s <= seg; ++s) {
            for (int j = 0; j < 11 && nb[s] < 11; ++j) {
                int e2[11] = {}; int n2 = 0;
                for (int i = 0; i < nb[s]; ++i) {
                    const int rr = reduce_ech(C[s].col[i], e2, n2);
                    if (rr) e2[n2++] = rr;
                }
                if (reduce_ech(1 << j, e2, n2) != 0) C[s].col[nb[s]++] = 1 << j;
            }
            if (nb[s] != 11) P.ok = 0;
        }
    }
    // ---- pass 2: per-gate constants ----
    {
        M11 IC[MAXSEG] = {};
        for (int s = 0; s <= lastseg; ++s) {
            IC[s] = inv11(C[s]);
            for (int i = 0; i < 11; ++i)
                if (mapv(IC[s], C[s].col[i]) != (1 << i)) P.ok = 0;
        }
        int cur = 0;
        for (int g = 0; g < NGATES; ++g) {
            const int L = g / 11, b = 10 - g % 11;
            const int m = mask_of(L, b), rw = row_of(L, b);
            if (P.kind[g] == 0) {
                const int tm = mapv(IC[cur], m);
                P.tmask[g] = tm;
                int tr = 0;
                for (int i = 0; i < 11; ++i) tr |= par11(rw & C[cur].col[i]) << i;
                P.trow[g] = tr;
                if ((tm >> 9) != 0 || tm == 0) P.ok = 0;
                if (par11(tr & tm) != 1) P.ok = 0;
            } else {
                const int so = cur, sn = cur + 1;
                for (int i = 0; i < 11; ++i)
                    P.gcol[g][i] = rotv(mapv(IC[so], C[sn].col[i]));
                P.dslot[g] = rotv(mapv(IC[so], m));
                int tr = 0;
                for (int i = 0; i < 11; ++i) tr |= par11(rw & C[sn].col[i]) << i;
                P.trow[g] = tr;
                cur = sn;
            }
        }
        if (cur != lastseg) P.ok = 0;
        for (int i = 0; i < 11; ++i) P.ucol[i] = ring_pow(C[cur].col[i], 5);
    }
    return P;
}

constexpr Plan PL = mkplan();
static_assert(PL.ok == 1, "layout plan construction failed");
static_assert(PL.ncuts == 6, "expected exactly 6 LDS exchanges");

// new = cA*x + cB*y (complex, 2 mul + 6 fma)
__device__ __forceinline__ c32 comb(c32 cA, c32 xx, c32 cB, c32 yy) {
    float re =  cA.re * xx.re;
    re = fmaf(-cA.im, xx.im, re);
    re = fmaf( cB.re, yy.re, re);
    re = fmaf(-cB.im, yy.im, re);
    float im =  cA.re * xx.im;
    im = fmaf( cA.im, xx.re, im);
    im = fmaf( cB.re, yy.im, im);
    im = fmaf( cB.im, yy.re, im);
    return { re, im };
}

// lane-XOR exchange: DPP quad_perm for masks 1/2/3 (VALU pipe, ~4cy),
// ds_swizzle via __shfl_xor otherwise (LDS pipe, ~64cy).
template<int MASK>
__device__ __forceinline__ float lane_xor_f(float x) {
    if constexpr (MASK == 1 || MASK == 2 || MASK == 3) {
        constexpr int ctrl = (MASK == 1) ? 0xB1 : (MASK == 2) ? 0x4E : 0x1B;
        return __int_as_float(__builtin_amdgcn_update_dpp(
            0, __float_as_int(x), ctrl, 0xf, 0xf, true));
    } else {
        return __shfl_xor(x, MASK, 64);
    }
}

// ---------------- wave-local gate (register pair or lane shuffle) --------------
// gsel[g][s] = side-s coefficient pair {own, partner}: s0 = {m00,m01}, s1 = {m11,m10}.
template<int g>
__device__ __forceinline__ void seg_gate(c32 (&a)[8], const c32x2 (*gsel)[2], int tid) {
    constexpr int TMv = PL.tmask[g];
    constexpr int TRv = PL.trow[g];
    constexpr int mr = TMv & 7;
    constexpr int mlane = (TMv >> 3) & 63;
    static_assert((TMv >> 9) == 0 && TMv != 0, "seg gate must be wave-local");

    const int sl = __popc(tid & (TRv >> 3)) & 1;
    const c32x2 P0 = gsel[g][sl];       // coefficient pair when reg-side-parity cr==0
    const c32x2 P1 = gsel[g][sl ^ 1];   // pair when cr==1

    if constexpr (mlane != 0 && mr == 0) {
#pragma unroll
        for (int r = 0; r < 8; ++r) {
            const c32 pv { lane_xor_f<mlane>(a[r].re), lane_xor_f<mlane>(a[r].im) };
            const int cr = __popc(r & (TRv & 7)) & 1;   // compile-time constant
            const c32x2 Pp = cr ? P1 : P0;
            a[r] = comb(Pp.a, a[r], Pp.b, pv);
        }
    } else if constexpr (mlane != 0) {
        constexpr int piv = mr & (-mr);
#pragma unroll
        for (int r0 = 0; r0 < 8; ++r0) if (!(r0 & piv)) {
            const int r1 = r0 ^ mr;
            const c32 o0 = a[r0], o1 = a[r1];
            const c32 pv0 { lane_xor_f<mlane>(o1.re), lane_xor_f<mlane>(o1.im) };
            const c32 pv1 { lane_xor_f<mlane>(o0.re), lane_xor_f<mlane>(o0.im) };
            const int cr0 = __popc(r0 & (TRv & 7)) & 1;
            const int cr1 = cr0 ^ (__popc(mr & (TRv & 7)) & 1);
            const c32x2 Pp0 = cr0 ? P1 : P0;
            const c32x2 Pp1 = cr1 ? P1 : P0;
            a[r0] = comb(Pp0.a, o0, Pp0.b, pv0);
            a[r1] = comb(Pp1.a, o1, Pp1.b, pv1);
        }
    } else {
        constexpr int piv = mr & (-mr);
#pragma unroll
        for (int r0 = 0; r0 < 8; ++r0) if (!(r0 & piv)) {
            const int r1 = r0 ^ mr;
            const c32 o0 = a[r0], o1 = a[r1];
            const int cr0 = __popc(r0 & (TRv & 7)) & 1;   // sides provably opposite
            const c32x2 Pp0 = cr0 ? P1 : P0;
            const c32x2 Pp1 = cr0 ? P0 : P1;
            a[r0] = comb(Pp0.a, o0, Pp0.b, o1);
            a[r1] = comb(Pp1.a, o1, Pp1.b, o0);
        }
    }
}

// ---------------- LDS-exchange gate + layout transition (one barrier) ----------
template<int g>
__device__ __forceinline__ void cut_gate(c32 (&a)[8], const c32x2 (*gsel)[2],
                                         c32* exA, c32* exB, int tid) {
    constexpr int TRv = PL.trow[g];
    constexpr int DS  = PL.dslot[g];
    constexpr int CI  = PL.cidx[g];
    constexpr int G0 = PL.gcol[g][0], G1 = PL.gcol[g][1], G2 = PL.gcol[g][2];
    constexpr int G3 = PL.gcol[g][3], G4 = PL.gcol[g][4], G5 = PL.gcol[g][5];
    constexpr int G6 = PL.gcol[g][6], G7 = PL.gcol[g][7], G8 = PL.gcol[g][8];
    constexpr int G9 = PL.gcol[g][9], G10 = PL.gcol[g][10];

    c32* buf = (CI & 1) ? exB : exA;
#pragma unroll
    for (int r = 0; r < 8; ++r) buf[(r << 8) | tid] = a[r];   // SoA: conflict-free
    __syncthreads();

    int base = 0;                               // old SoA slot of phys(C_new(tid<<3))
    base ^= (-((tid >> 0) & 1)) & G3;
    base ^= (-((tid >> 1) & 1)) & G4;
    base ^= (-((tid >> 2) & 1)) & G5;
    base ^= (-((tid >> 3) & 1)) & G6;
    base ^= (-((tid >> 4) & 1)) & G7;
    base ^= (-((tid >> 5) & 1)) & G8;
    base ^= (-((tid >> 6) & 1)) & G9;
    base ^= (-((tid >> 7) & 1)) & G10;

    const int sl = __popc(tid & (TRv >> 3)) & 1;
    const c32x2 P0 = gsel[g][sl];
    const c32x2 P1 = gsel[g][sl ^ 1];
#pragma unroll
    for (int r = 0; r < 8; ++r) {
        const int so = base ^ (((r & 1) ? G0 : 0) ^ ((r & 2) ? G1 : 0) ^ ((r & 4) ? G2 : 0));
        const c32 own = buf[so];
        const c32 par = buf[so ^ DS];
        const int cr = __popc(r & (TRv & 7)) & 1;
        const c32x2 Pp = cr ? P1 : P0;
        a[r] = comb(Pp.a, own, Pp.b, par);
    }
}

template<int g>
__device__ __forceinline__ void run_all(c32 (&a)[8], const c32x2 (*gsel)[2],
                                        c32* exA, c32* exB, int tid) {
    if constexpr (PL.kind[g] == 1) cut_gate<g>(a, gsel, exA, exB, tid);
    else                           seg_gate<g>(a, gsel, tid);
    if constexpr (g + 1 < NGATES) run_all<g + 1>(a, gsel, exA, exB, tid);
}

__global__ __launch_bounds__(256) void qsim_kernel(
    const float* __restrict__ x,   // [B,1,NQ] f32
    const float* __restrict__ w,   // [198] f32
    float* __restrict__ out)       // f32: [B,32,32] REAL block, then IMAG block
{
    __shared__ __align__(16) c32 exA[DIM];
    __shared__ __align__(16) c32 exB[DIM];
    __shared__ c32x2 gsel[NGATES][2];   // [gate][side] = {own, partner} coef pair

    const int b = blockIdx.x;
    const int tid = threadIdx.x;

    // ---- fused YZY matrices (embedding folded into layer 0) ----
    if (tid < NGATES) {
        const int l = tid / NQ, q = tid % NQ;
        const float* p = &w[l * 3 * NQ + q * 3];
        float c0, s0, cz, sz, c2, s2;
        sincosf(0.5f * p[0], &s0, &c0);
        sincosf(0.5f * p[1], &sz, &cz);
        sincosf(0.5f * p[2], &s2, &c2);
        c32 A00 = {  cz * c0, -sz * c0 };
        c32 A01 = { -cz * s0,  sz * s0 };
        c32 A10 = {  cz * s0,  sz * s0 };
        c32 A11 = {  cz * c0,  sz * c0 };
        c32 M00 = { c2 * A00.re - s2 * A10.re, c2 * A00.im - s2 * A10.im };
        c32 M01 = { c2 * A01.re - s2 * A11.re, c2 * A01.im - s2 * A11.im };
        c32 M10 = { s2 * A00.re + c2 * A10.re, s2 * A00.im + c2 * A10.im };
        c32 M11 = { s2 * A01.re + c2 * A11.re, s2 * A01.im + c2 * A11.im };
        if (l == 0) {
            float ce, se;
            sincosf(0.5f * x[b * NQ + q], &se, &ce);
            c32 N00 = { M00.re * ce + M01.re * se, M00.im * ce + M01.im * se };
            c32 N01 = { M01.re * ce - M00.re * se, M01.im * ce - M00.im * se };
            c32 N10 = { M10.re * ce + M11.re * se, M10.im * ce + M11.im * se };
            c32 N11 = { M11.re * ce - M10.re * se, M11.im * ce - M10.im * se };
            M00 = N00; M01 = N01; M10 = N10; M11 = N11;
        }
        gsel[tid][0] = { M00, M01 };   // side 0: own = m00, partner = m01
        gsel[tid][1] = { M11, M10 };   // side 1: own = m11, partner = m10
    }

    // ---- |0...0>, 8 amplitudes per lane in registers (phys 0 -> t 0 always) ----
    c32 a[8];
#pragma unroll
    for (int r = 0; r < 8; ++r) a[r] = { 0.f, 0.f };
    if (tid == 0) a[0].re = 1.f;
    __syncthreads();

    // ---- full circuit: 21 register gates + 39 lane-exchange gates + 6 LDS cuts ----
    run_all<0>(a, gsel, exA, exB, tid);

    // ---- unscramble to logical order: logical = R^5(C_last(t)) ----
    constexpr int U0 = PL.ucol[0], U1 = PL.ucol[1], U2 = PL.ucol[2];
    constexpr int U3 = PL.ucol[3], U4 = PL.ucol[4], U5 = PL.ucol[5];
    constexpr int U6 = PL.ucol[6], U7 = PL.ucol[7], U8 = PL.ucol[8];
    constexpr int U9 = PL.ucol[9], U10 = PL.ucol[10];
    c32* fb = (PL.ncuts & 1) ? exB : exA;     // the buffer NOT used by the last cut
    int T = 0;
    T ^= (-((tid >> 0) & 1)) & U3;
    T ^= (-((tid >> 1) & 1)) & U4;
    T ^= (-((tid >> 2) & 1)) & U5;
    T ^= (-((tid >> 3) & 1)) & U6;
    T ^= (-((tid >> 4) & 1)) & U7;
    T ^= (-((tid >> 5) & 1)) & U8;
    T ^= (-((tid >> 6) & 1)) & U9;
    T ^= (-((tid >> 7) & 1)) & U10;
#pragma unroll
    for (int r = 0; r < 8; ++r) {
        const int off = ((r & 1) ? U0 : 0) ^ ((r & 2) ? U1 : 0) ^ ((r & 4) ? U2 : 0);
        fb[T ^ off] = a[r];
    }
    __syncthreads();

    // ---- partial trace keeping the LAST 5 qubits (low bits) ----
    // rho[b][j][k] = sum_{i<64} psi[i*32+j] * conj(psi[i*32+k]); 2x2 block/thread.
    // j0,k0 even -> 16B-aligned pairs -> ds_read_b128.
    const int j0 = (tid >> 4) << 1, k0 = (tid & 15) << 1;
    float r00re = 0.f, r00im = 0.f, r01re = 0.f, r01im = 0.f;
    float r10re = 0.f, r10im = 0.f, r11re = 0.f, r11im = 0.f;
#pragma unroll 8
    for (int i = 0; i < 64; i++) {
        const float4 Av = *reinterpret_cast<const float4*>(&fb[i * 32 + j0]);
        const float4 Bv = *reinterpret_cast<const float4*>(&fb[i * 32 + k0]);
        const c32 A0 { Av.x, Av.y }, A1 { Av.z, Av.w };
        const c32 B0 { Bv.x, Bv.y }, B1 { Bv.z, Bv.w };
        r00re = fmaf(A0.re, B0.re, fmaf( A0.im, B0.im, r00re));
        r00im = fmaf(A0.im, B0.re, fmaf(-A0.re, B0.im, r00im));
        r01re = fmaf(A0.re, B1.re, fmaf( A0.im, B1.im, r01re));
        r01im = fmaf(A0.im, B1.re, fmaf(-A0.re, B1.im, r01im));
        r10re = fmaf(A1.re, B0.re, fmaf( A1.im, B0.im, r10re));
        r10im = fmaf(A1.im, B0.re, fmaf(-A1.re, B0.im, r10im));
        r11re = fmaf(A1.re, B1.re, fmaf( A1.im, B1.im, r11re));
        r11im = fmaf(A1.im, B1.re, fmaf(-A1.re, B1.im, r11im));
    }
    // PLANAR f32 layout: real block [0,16384), imag block [16384,32768).
    float* o = out + b * 1024;
    *reinterpret_cast<float2*>(&o[ j0      * 32 + k0]) = make_float2(r00re, r01re);
    *reinterpret_cast<float2*>(&o[(j0 + 1) * 32 + k0]) = make_float2(r10re, r11re);
    o += 16384;
    *reinterpret_cast<float2*>(&o[ j0      * 32 + k0]) = make_float2(r00im, r01im);
    *reinterpret_cast<float2*>(&o[(j0 + 1) * 32 + k0]) = make_float2(r10im, r11im);
}

extern "C" void kernel_launch(void* const* d_in, const int* in_sizes, int n_in,
                              void* d_out, int out_size, void* d_ws, size_t ws_size,
                              hipStream_t stream) {
    const float* x = (const float*)d_in[0];   // [B,1,NQ] f32
    const float* w = (const float*)d_in[1];   // [198] f32
    float* out = (float*)d_out;
    qsim_kernel<<<16, 256, 0, stream>>>(x, w, out);
}